// Round 4
// baseline (158.019 us; speedup 1.0000x reference)
//
#include <hip/hip_runtime.h>
#include <stdint.h>

#define Bb 32
#define Nn 256
#define Ee 8
#define Ff 16
#define K1 32

typedef unsigned long long u64;
typedef float f32x4 __attribute__((ext_vector_type(4)));

// Kernel A: adjacency floats -> 256-bit row bitmasks. One wave per (b,r).
__global__ void bitmask_kernel(const float* __restrict__ adj, u64* __restrict__ bm) {
    int wave = (blockIdx.x << 2) + (threadIdx.x >> 6);   // (b*N + r), 4 waves/block
    int lane = threadIdx.x & 63;
    const float* row = adj + (size_t)wave * Nn;
#pragma unroll
    for (int w = 0; w < 4; ++w) {
        float v = row[w * 64 + lane];
        u64 m = __ballot(v != 0.0f);
        if (lane == 0) bm[(size_t)wave * 4 + w] = m;
    }
}

// Fused kernel: per-block BFS (thread 0) + gather of all three outputs.
// One block per (b,s).
__global__ void fused_kernel(const f32x4* __restrict__ e4,
                             const f32x4* __restrict__ feats4,
                             const u64* __restrict__ bm,
                             float* __restrict__ out) {
    int bs = blockIdx.x;
    int b = bs >> 8;
    int s = bs & 255;
    int t = threadIdx.x;
    __shared__ u64 bml[Nn * 4];   // 8 KB: all bitmask rows of this batch
    __shared__ int p[K1];

    // load batch bitmask into LDS (L2-resident: 8 KB reused by 256 blocks)
#pragma unroll
    for (int k = 0; k < 4; ++k) bml[t + k * 256] = bm[(size_t)b * 1024 + t + k * 256];
    __syncthreads();

    // serial BFS for this block's start vertex (matches reference FIFO order:
    // neighbours enqueued ascending, dedup vs seen; only first 32 kept)
    if (t == 0) {
        u64 seen[4];
#pragma unroll
        for (int w = 0; w < 4; ++w) seen[w] = (w == (s >> 6)) ? (1ull << (s & 63)) : 0ull;
        uint8_t order[K1];
        order[0] = (uint8_t)s;
        int count = 1;
        for (int i = 0; i < count && count < K1; ++i) {
            int cur = order[i];
#pragma unroll
            for (int w = 0; w < 4; ++w) {
                u64 nw = bml[cur * 4 + w] & ~seen[w];
                seen[w] |= nw;   // extras past 32 harmless (never dequeued)
                while (nw) {
                    int bit = __builtin_ctzll(nw);
                    nw &= nw - 1;
                    if (count < K1) order[count++] = (uint8_t)(w * 64 + bit);
                    else break;
                }
            }
        }
#pragma unroll
        for (int i = 0; i < K1; ++i) p[i] = order[i];
    }
    __syncthreads();

    // ---- sub_adj: (K1,K1) floats, 256 f32x4 per block ----
    f32x4* out0 = (f32x4*)(out) + (size_t)bs * 256;
    {
        int i = t >> 3;
        int pi4 = p[i] * 4;
        int j0 = (t & 7) * 4;
        f32x4 a;
        int pj;
        pj = p[j0 + 0]; a.x = (float)((bml[pi4 + (pj >> 6)] >> (pj & 63)) & 1ull);
        pj = p[j0 + 1]; a.y = (float)((bml[pi4 + (pj >> 6)] >> (pj & 63)) & 1ull);
        pj = p[j0 + 2]; a.z = (float)((bml[pi4 + (pj >> 6)] >> (pj & 63)) & 1ull);
        pj = p[j0 + 3]; a.w = (float)((bml[pi4 + (pj >> 6)] >> (pj & 63)) & 1ull);
        out0[t] = a;
    }

    // ---- sub_feats: (K1,F) floats, 128 f32x4 per block ----
    f32x4* out2 = (f32x4*)(out + 75497472ull) + (size_t)bs * 128;
    if (t < 128) {
        int i = t >> 2, f4 = t & 3;
        out2[t] = feats4[((size_t)b * 256 + p[i]) * 4 + f4];
    }

    // ---- sub_edges: (K1,K1,E) floats, 2048 f32x4 per block ----
    f32x4* out1 = (f32x4*)(out + 8388608ull) + (size_t)bs * 2048;
#pragma unroll
    for (int k = 0; k < 8; ++k) {
        int v = t + k * 256;
        int i = v >> 6, j = (v >> 1) & 31, h = v & 1;
        int pi = p[i], pj = p[j];
        bool m = (bml[pi * 4 + (pj >> 6)] >> (pj & 63)) & 1ull;
        f32x4 val = (f32x4){0.f, 0.f, 0.f, 0.f};
        if (m) val = e4[(((size_t)b * 256 + pi) * 256 + pj) * 2 + h];
        out1[v] = val;
    }
}

extern "C" void kernel_launch(void* const* d_in, const int* in_sizes, int n_in,
                              void* d_out, int out_size, void* d_ws, size_t ws_size,
                              hipStream_t stream) {
    const float* adj   = (const float*)d_in[0];
    const float* edges = (const float*)d_in[1];
    const float* feats = (const float*)d_in[2];
    float* out = (float*)d_out;

    u64* bm = (u64*)d_ws;   // 262144 B

    bitmask_kernel<<<Bb * Nn / 4, 256, 0, stream>>>(adj, bm);
    fused_kernel<<<Bb * Nn, 256, 0, stream>>>((const f32x4*)edges, (const f32x4*)feats,
                                              bm, out);
}

// Round 5
// 89.872 us; speedup vs baseline: 1.7583x; 1.7583x over previous
//
#include <hip/hip_runtime.h>
#include <stdint.h>

#define Bb 32
#define Nn 256
#define Ee 8
#define Ff 16
#define K1 32

typedef unsigned long long u64;
typedef float f32x4 __attribute__((ext_vector_type(4)));

// Kernel A: adjacency floats -> 256-bit row bitmasks. One wave per (b,r).
__global__ void bitmask_kernel(const float* __restrict__ adj, u64* __restrict__ bm) {
    int wave = (blockIdx.x << 2) + (threadIdx.x >> 6);   // (b*N + r), 4 waves/block
    int lane = threadIdx.x & 63;
    const float* row = adj + (size_t)wave * Nn;
#pragma unroll
    for (int w = 0; w < 4; ++w) {
        float v = row[w * 64 + lane];
        u64 m = __ballot(v != 0.0f);
        if (lane == 0) bm[(size_t)wave * 4 + w] = m;
    }
}

// Kernel B: per-thread BFS. 128 blocks x 64 threads (4 blocks per batch).
// Queues live in LDS (NOT per-thread arrays -> would spill to scratch).
__global__ void bfs_kernel(const u64* __restrict__ bm, uint32_t* __restrict__ proc32) {
    __shared__ u64 bml[Nn * 4];          // 8 KB: bitmask rows for this batch
    __shared__ uint8_t order[64 * K1];   // 2 KB: BFS order for this block's 64 starts
    int b = blockIdx.x >> 2;
    int g = blockIdx.x & 3;
    int t = threadIdx.x;                 // 0..63
#pragma unroll
    for (int k = 0; k < 16; ++k) bml[t + k * 64] = bm[(size_t)b * 1024 + t + k * 64];
    __syncthreads();

    int s = g * 64 + t;                  // this thread's start vertex
    u64 seen[4];
#pragma unroll
    for (int w = 0; w < 4; ++w) seen[w] = (w == (s >> 6)) ? (1ull << (s & 63)) : 0ull;
    order[t * K1] = (uint8_t)s;
    int count = 1;
    for (int i = 0; i < count && count < K1; ++i) {
        int cur = order[t * K1 + i];
#pragma unroll
        for (int w = 0; w < 4; ++w) {
            u64 nw = bml[cur * 4 + w] & ~seen[w];
            seen[w] |= nw;   // extras past 32 harmless (never dequeued)
            while (nw) {
                int bit = __builtin_ctzll(nw);
                nw &= nw - 1;
                if (count < K1) order[t * K1 + count++] = (uint8_t)(w * 64 + bit);
                else break;
            }
        }
    }
    __syncthreads();
    const uint32_t* ord32 = (const uint32_t*)order;
#pragma unroll
    for (int k = 0; k < 8; ++k)
        proc32[(size_t)b * 2048 + g * 512 + t + k * 64] = ord32[t + k * 64];
}

// Kernel C: gather all three outputs. One block per (b,s), XCD-swizzled.
__global__ void gather_kernel(const f32x4* __restrict__ e4,
                              const f32x4* __restrict__ feats4,
                              const u64* __restrict__ bm,
                              const uint32_t* __restrict__ proc32,
                              float* __restrict__ out) {
    // T1: bijective XCD swizzle (8192 % 8 == 0). Each XCD owns 1024
    // consecutive bs = 4 whole batches -> batch working set on ONE L2.
    int bid = blockIdx.x;
    int bs = ((bid & 7) << 10) | (bid >> 3);
    int b = bs >> 8;
    int t = threadIdx.x;
    __shared__ int p[K1];
    __shared__ u64 bmrow[K1][4];

    if (t < 8) {
        uint32_t w = proc32[(size_t)bs * 8 + t];
        p[t * 4 + 0] = w & 255;
        p[t * 4 + 1] = (w >> 8) & 255;
        p[t * 4 + 2] = (w >> 16) & 255;
        p[t * 4 + 3] = (w >> 24) & 255;
    }
    __syncthreads();
    if (t < 128) {
        int i = t >> 2, w = t & 3;
        bmrow[i][w] = bm[((size_t)b * 256 + p[i]) * 4 + w];
    }
    __syncthreads();

    // ---- sub_adj: (K1,K1) floats, 256 f32x4 per block ----
    f32x4* out0 = (f32x4*)(out) + (size_t)bs * 256;
    {
        int i = t >> 3;
        int j0 = (t & 7) * 4;
        f32x4 a;
        int pj;
        pj = p[j0 + 0]; a.x = (float)((bmrow[i][pj >> 6] >> (pj & 63)) & 1ull);
        pj = p[j0 + 1]; a.y = (float)((bmrow[i][pj >> 6] >> (pj & 63)) & 1ull);
        pj = p[j0 + 2]; a.z = (float)((bmrow[i][pj >> 6] >> (pj & 63)) & 1ull);
        pj = p[j0 + 3]; a.w = (float)((bmrow[i][pj >> 6] >> (pj & 63)) & 1ull);
        out0[t] = a;
    }

    // ---- sub_feats: (K1,F) floats, 128 f32x4 per block ----
    f32x4* out2 = (f32x4*)(out + 75497472ull) + (size_t)bs * 128;
    if (t < 128) {
        int i = t >> 2, f4 = t & 3;
        out2[t] = feats4[((size_t)b * 256 + p[i]) * 4 + f4];
    }

    // ---- sub_edges: (K1,K1,E) floats, 2048 f32x4 per block ----
    // Branchless masked gather: all 8 loads issued up-front (address 0 for
    // masked-off lanes stays L1-hot), zero-select after. No exec-mask branches.
    f32x4* out1 = (f32x4*)(out + 8388608ull) + (size_t)bs * 2048;
    f32x4 vals[8];
#pragma unroll
    for (int k = 0; k < 8; ++k) {
        int v = t + k * 256;
        int i = v >> 6, j = (v >> 1) & 31, h = v & 1;
        int pi = p[i], pj = p[j];
        bool m = (bmrow[i][pj >> 6] >> (pj & 63)) & 1ull;
        size_t idx = m ? ((((size_t)b * 256 + pi) * 256 + pj) * 2 + h) : 0;
        f32x4 val = e4[idx];
        vals[k] = m ? val : (f32x4){0.f, 0.f, 0.f, 0.f};
    }
#pragma unroll
    for (int k = 0; k < 8; ++k)
        out1[t + k * 256] = vals[k];
}

extern "C" void kernel_launch(void* const* d_in, const int* in_sizes, int n_in,
                              void* d_out, int out_size, void* d_ws, size_t ws_size,
                              hipStream_t stream) {
    const float* adj   = (const float*)d_in[0];
    const float* edges = (const float*)d_in[1];
    const float* feats = (const float*)d_in[2];
    float* out = (float*)d_out;

    u64* bm = (u64*)d_ws;                                          // 262144 B
    uint32_t* proc32 = (uint32_t*)((char*)d_ws + (size_t)Bb * Nn * 4 * sizeof(u64));

    bitmask_kernel<<<Bb * Nn / 4, 256, 0, stream>>>(adj, bm);
    bfs_kernel<<<Bb * 4, 64, 0, stream>>>(bm, proc32);
    gather_kernel<<<Bb * Nn, 256, 0, stream>>>((const f32x4*)edges, (const f32x4*)feats,
                                               bm, proc32, out);
}